// Round 8
// baseline (681.696 us; speedup 1.0000x reference)
//
#include <hip/hip_runtime.h>
#include <math.h>

typedef __attribute__((ext_vector_type(8))) short bf16x8;
typedef __attribute__((ext_vector_type(4))) float f32x4;
typedef __attribute__((ext_vector_type(4))) unsigned int u32x4;

__device__ __forceinline__ unsigned f2bf(float f) {
    union { float f; unsigned u; } v; v.f = f;
    return (v.u + 0x7FFFu + ((v.u >> 16) & 1u)) >> 16;   // RTNE bf16
}

// counted wait: vmcnt(VM) lgkmcnt(LG), then fence scheduler (rule #18)
template<int VM, int LG>
__device__ __forceinline__ void waitcnt_fence() {
    __builtin_amdgcn_s_waitcnt((VM & 15) | (7 << 4) | (LG << 8));
    __builtin_amdgcn_sched_barrier(0);
}

// Build conv kernel in bf16, layout Kb[tap][o][i] (i contiguous), taps 0..125
// with tap 125 all-zero (pad for tap-pairing). Self-interaction folded into
// center tap (62), x10 since out = 0.1*conv_total.
__global__ __launch_bounds__(256) void build_K(
    const float* __restrict__ w_lin0,
    const float* __restrict__ w_lin1,
    const float* __restrict__ tp_weight,
    unsigned short* __restrict__ Kb)
{
    const int tid = (int)threadIdx.x;
    const int tap = (int)blockIdx.x;            // 0..125
    if (tap == 125) {
        for (int n = tid; n < 4096; n += 256) Kb[125 * 4096 + n] = 0;
        return;
    }
    const int i1 = tap / 25, i2 = (tap / 5) % 5, i3 = tap % 5;
    const float X = -1.0f + 0.5f * (float)i1;
    const float Y = -1.0f + 0.5f * (float)i2;
    const float Z = -1.0f + 0.5f * (float)i3;
    const float d = sqrtf(X*X + Y*Y + Z*Z);
    const float dinv = 1.0f / fmaxf(d, 1e-12f);
    const float vx = X * dinv, vy = Y * dinv, vz = Z * dinv;
    const float r2 = vx*vx + vy*vy + vz*vz;

    __shared__ float wsh[1280];
    __shared__ float y1s[3];
    __shared__ float Qs[9];

    if (tid == 0) {
        const float s3 = 1.7320508075688772f;
        const float s15 = 3.872983346207417f;
        y1s[0] = s3 * vy; y1s[1] = s3 * vz; y1s[2] = s3 * vx;
        float y2v0 = s15 * vx * vy;
        float y2v1 = s15 * vy * vz;
        float y2v2 = 1.118033988749895f * (3.0f * vz * vz - r2);
        float y2v3 = s15 * vx * vz;
        float y2v4 = 1.9364916731037085f * (vx * vx - vy * vy);
        const float INV10 = 0.31622776601683794f;
        const float INV30 = 0.18257418583505536f;
        Qs[0] = -y2v2 * INV30 - y2v4 * INV10;
        Qs[4] =  2.0f * y2v2 * INV30;
        Qs[8] = -y2v2 * INV30 + y2v4 * INV10;
        Qs[1] = Qs[3] = y2v1 * INV10;
        Qs[2] = Qs[6] = y2v0 * INV10;
        Qs[5] = Qs[7] = y2v3 * INV10;
    }

    float emb[5];
    #pragma unroll
    for (int e = 0; e < 5; ++e) {
        float t = (d - 0.25f * (float)e) * 4.0f;
        emb[e] = expf(-t * t) * (1.0f / 1.12f);
    }
    const float scale = cosf(3.14159265358979323846f * d) / 11.180339887498949f;

    for (int j = tid; j < 1280; j += 256) {
        float s = 0.0f;
        #pragma unroll
        for (int e = 0; e < 5; ++e) s += emb[e] * tp_weight[e * 1280 + j];
        wsh[j] = scale * s;
    }
    __syncthreads();

    const float F0   = 0.17677669529663687f;
    const float F1   = 0.25f;
    const float F0S3 = 0.10206207261596574f;
    const float F1S3 = 0.14433756729740646f;

    #pragma unroll 1
    for (int n = 0; n < 16; ++n) {
        int e = n * 256 + tid;
        int o = e & 63, i = e >> 6;
        float Kv;
        if (o < 16) {
            if (i < 16) {
                Kv = F0 * wsh[0 * 256 + i * 16 + o];
            } else {
                int u = (i - 16) / 3, a = (i - 16) % 3;
                Kv = F0S3 * y1s[a] * wsh[3 * 256 + u * 16 + o];
            }
        } else {
            int wcol = (o - 16) / 3, c = (o - 16) % 3;
            if (i < 16) {
                Kv = F1S3 * y1s[c] * wsh[1 * 256 + i * 16 + wcol];
            } else {
                int u = (i - 16) / 3, a = (i - 16) % 3;
                Kv = F1 * Qs[a * 3 + c] * wsh[4 * 256 + u * 16 + wcol];
                if (a == c) Kv += F1S3 * wsh[2 * 256 + u * 16 + wcol];
            }
        }
        if (tap == 62) {
            if (o < 16) {
                if (i < 16) Kv += 2.5f * w_lin0[i * 16 + o];
            } else if (i >= 16) {
                int v = (o - 16) / 3, m = (o - 16) % 3;
                int u = (i - 16) / 3, a = (i - 16) % 3;
                if (a == m) Kv += 2.5f * w_lin1[u * 16 + v];
            }
        }
        Kb[(tap * 64 + o) * 64 + i] = (unsigned short)f2bf(Kv);
    }
}

// Pre-pass: x fp32 [b][c][32^3] -> xbz bf16 channel-last [b][pos][64ch],
// preceded by a 128B zero page (for OOB halo lanes).
__global__ __launch_bounds__(256) void to_blc(
    const float* __restrict__ x,
    unsigned short* __restrict__ xbz)
{
    const int tid = (int)threadIdx.x, blk = (int)blockIdx.x;
    if (blk == 0 && tid < 64) xbz[tid] = 0;          // zero page
    const int p = blk * 256 + tid;                   // 0..131071
    const int b = p >> 15, pos = p & 32767;
    const float* xp = x + ((size_t)b << 21) + pos;
    unsigned short* op = xbz + 64 + (size_t)p * 64;
    #pragma unroll
    for (int cg = 0; cg < 8; ++cg) {
        u32x4 dv;
        #pragma unroll
        for (int jj = 0; jj < 4; ++jj) {
            float f0 = xp[((size_t)(cg * 8 + 2 * jj)) << 15];
            float f1 = xp[((size_t)(cg * 8 + 2 * jj + 1)) << 15];
            dv[jj] = f2bf(f0) | (f2bf(f1) << 16);
        }
        *(u32x4*)(op + cg * 8) = dv;
    }
}

// One K-step (tap pair P), fully pipelined via inline asm:
//  - issue A-fragment loads for pair P+3 (ring 4 slots, distance 3)
//  - issue xn ds_reads for pair P+1 (ring 2 slots, distance 1)
//  - counted s_waitcnt vmcnt/lgkmcnt + sched_barrier
//  - 8 MFMAs for pair P
template<int P>
__device__ __forceinline__ void kstep(
    const void* kb_s, unsigned klane,
    const int (&nbase)[4], const int (&sax)[5], bool thv,
    bf16x8 (&Ab)[4][2], bf16x8 (&xn)[2][4], f32x4 (&acc)[2][4])
{
    if constexpr (P + 3 < 63) {
        #pragma unroll
        for (int m = 0; m < 2; ++m) {
            unsigned voff = klane + (unsigned)((P + 3) * 16384 + m * 2048);
            asm volatile("global_load_dwordx4 %0, %1, %2"
                         : "=v"(Ab[(P + 3) & 3][m])
                         : "v"(voff), "s"(kb_s));
        }
    }
    if constexpr (P + 1 < 63) {
        constexpr int t0 = 2 * (P + 1);
        constexpr int t1 = (2 * (P + 1) + 1 == 125) ? 124 : 2 * (P + 1) + 1;
        int pdA = (t0 / 25) * 4608 + ((t0 / 5) % 5) * 384;
        int pdB = (t1 / 25) * 4608 + ((t1 / 5) % 5) * 384;
        int pd = thv ? (pdB + sax[t1 % 5]) : (pdA + sax[t0 % 5]);
        #pragma unroll
        for (int n = 0; n < 4; ++n) {
            unsigned a = (unsigned)(nbase[n] + pd);
            asm volatile("ds_read_b128 %0, %1"
                         : "=v"(xn[(P + 1) & 1][n]) : "v"(a));
        }
    }
    constexpr int VM = (P + 3 < 63) ? 6 : (62 - P) * 2;
    constexpr int LG = (P + 1 < 63) ? 4 : 0;
    waitcnt_fence<VM, LG>();
    #pragma unroll
    for (int m = 0; m < 2; ++m)
        #pragma unroll
        for (int n = 0; n < 4; ++n)
            acc[m][n] = __builtin_amdgcn_mfma_f32_16x16x32_bf16(
                Ab[P & 3][m], xn[P & 1][n], acc[m][n], 0, 0, 0);
    if constexpr (P + 1 < 63)
        kstep<P + 1>(kb_s, klane, nbase, sax, thv, Ab, xn, acc);
}

// Implicit-GEMM conv via MFMA 16x16x32 bf16, asm-pipelined K-loop.
// grid 1024, block = 2z x 8y x 8x = 128 pos, all 64 o, 4 waves.
// Wave (zp = wv>>1, h = wv&1): 2 mo x 4 np, acc 32 VGPR. Single 27.6 KB
// LDS x-tile (XOR-16 swizzle) staged via global_load_lds.
__global__ __launch_bounds__(256, 4) void conv_mfma(
    const unsigned short* __restrict__ xbz,
    const unsigned short* __restrict__ Kb,
    float* __restrict__ out)
{
    __shared__ __align__(16) char xs[27648];   // [6z][12y][12x] * 32B

    const int tid = (int)threadIdx.x;
    const int blk = (int)blockIdx.x;
    const int xt = blk & 3, yt = (blk >> 2) & 3, zt = (blk >> 4) & 15, b = blk >> 8;
    const int lane = tid & 63, wv = tid >> 6;
    const int r = lane & 15, g = lane >> 4;
    const int thalf = g >> 1, chslot = g & 1;
    const bool thv = (thalf != 0);
    const int zp = wv >> 1, h = wv & 1;

    // ---- staging source offsets (7 chunks/thread; 1728 chunks total) ----
    unsigned srcOff[7];
    {
        const int gz0 = zt * 2 - 2, gy0 = yt * 8 - 2, gx0 = xt * 8 - 2;
        #pragma unroll
        for (int i = 0; i < 7; ++i) {
            int tau = tid + i * 256;
            int pos = tau >> 1, slot = tau & 1;
            int hz = pos / 144; int rem = pos - hz * 144;
            int hy = rem / 12;  int hx = rem - hy * 12;
            int gz = gz0 + hz, gy = gy0 + hy, gx = gx0 + hx;
            bool ok = ((unsigned)gz < 32u) && ((unsigned)gy < 32u) && ((unsigned)gx < 32u);
            int pg = (gz << 10) + (gy << 5) + gx;
            unsigned chs = (unsigned)(slot ^ ((hx >> 2) & 1));  // swizzle-inverse
            srcOff[i] = ok ? (unsigned)(128 + (((b << 15) + pg) << 7) + chs * 16)
                           : (unsigned)(slot * 16);             // zero page
        }
    }

    // ---- per-lane swizzled x/ch part for dx=0..4 ----
    int sax[5];
    #pragma unroll
    for (int dx = 0; dx < 5; ++dx) {
        int xx = (r & 7) + dx;
        sax[dx] = (xx * 32 + chslot * 16) ^ ((xx & 4) << 2);
    }
    // per-np base (z-plane + y part)
    int nbase[4];
    #pragma unroll
    for (int n = 0; n < 4; ++n)
        nbase[n] = zp * 4608 + (2 * n + (r >> 3)) * 384;

    // A-side: SGPR base = Kb (+stage*32), per-lane 32-bit voffset
    const unsigned klane =
        (unsigned)(r * 128 + thalf * 8192 + chslot * 16 + h * 4096);

    f32x4 acc[2][4];
    #pragma unroll
    for (int m = 0; m < 2; ++m)
        #pragma unroll
        for (int n = 0; n < 4; ++n) acc[m][n] = (f32x4)0.0f;

    #pragma unroll 1
    for (int stage = 0; stage < 4; ++stage) {
        __syncthreads();                  // prev stage's LDS reads complete
        #pragma unroll
        for (int i = 0; i < 7; ++i) {
            if (tid + i * 256 < 1728) {
                const char* src = (const char*)xbz + srcOff[i] + stage * 32;
                __builtin_amdgcn_global_load_lds(
                    (const __attribute__((address_space(1))) unsigned int*)src,
                    (__attribute__((address_space(3))) unsigned int*)
                        (xs + i * 4096 + wv * 1024),
                    16, 0, 0);
            }
        }
        __syncthreads();                  // staging complete (vmcnt drained)

        const void* kb_s = (const void*)((const char*)Kb + stage * 32);

        // prologue: A pairs 0..2 (6 loads), xn pair 0 (4 ds_reads)
        bf16x8 Ab[4][2];
        #pragma unroll
        for (int pf = 0; pf < 3; ++pf)
            #pragma unroll
            for (int m = 0; m < 2; ++m) {
                unsigned voff = klane + (unsigned)(pf * 16384 + m * 2048);
                asm volatile("global_load_dwordx4 %0, %1, %2"
                             : "=v"(Ab[pf][m]) : "v"(voff), "s"(kb_s));
            }
        bf16x8 xn[2][4];
        {
            int pd = thv ? sax[1] : sax[0];     // pair 0: taps 0 (dx0) / 1 (dx1)
            #pragma unroll
            for (int n = 0; n < 4; ++n) {
                unsigned a = (unsigned)(nbase[n] + pd);
                asm volatile("ds_read_b128 %0, %1"
                             : "=v"(xn[0][n]) : "v"(a));
            }
        }

        kstep<0>(kb_s, klane, nbase, sax, thv, Ab, xn, acc);
    }

    // epilogue: D row = o-in-half = g*4+reg, col = pos-in-np-tile = r
    const int gz = zt * 2 + zp;
    #pragma unroll
    for (int m = 0; m < 2; ++m) {
        #pragma unroll
        for (int reg = 0; reg < 4; ++reg) {
            int o = h * 32 + m * 16 + g * 4 + reg;
            float* op = out + (((size_t)(b * 64 + o)) << 15) + (gz << 10);
            #pragma unroll
            for (int n = 0; n < 4; ++n) {
                int ly = 2 * n + (r >> 3), lx = r & 7;
                op[((yt * 8 + ly) << 5) + (xt * 8 + lx)] = 0.1f * acc[m][n][reg];
            }
        }
    }
}

extern "C" void kernel_launch(void* const* d_in, const int* in_sizes, int n_in,
                              void* d_out, int out_size, void* d_ws, size_t ws_size,
                              hipStream_t stream) {
    const float* x       = (const float*)d_in[0];
    const float* w_lin0  = (const float*)d_in[1];
    const float* w_lin1  = (const float*)d_in[2];
    const float* tp      = (const float*)d_in[3];
    unsigned short* Kb  = (unsigned short*)d_ws;                        // ~1.03 MB
    unsigned short* xbz = (unsigned short*)((char*)d_ws + (2u << 20));  // 128B zeros + 16.8MB bf16 x
    float* out = (float*)d_out;

    build_K<<<126, 256, 0, stream>>>(w_lin0, w_lin1, tp, Kb);
    to_blc<<<512, 256, 0, stream>>>(x, xbz);
    conv_mfma<<<1024, 256, 0, stream>>>(xbz, Kb, out);
}

// Round 9
// 319.276 us; speedup vs baseline: 2.1351x; 2.1351x over previous
//
#include <hip/hip_runtime.h>
#include <math.h>

typedef __attribute__((ext_vector_type(8))) short bf16x8;
typedef __attribute__((ext_vector_type(4))) float f32x4;
typedef __attribute__((ext_vector_type(4))) unsigned int u32x4;

#define KB_LDS 55296   // x-halo region size; Kb ring lives above it

__device__ __forceinline__ unsigned f2bf(float f) {
    union { float f; unsigned u; } v; v.f = f;
    return (v.u + 0x7FFFu + ((v.u >> 16) & 1u)) >> 16;   // RTNE bf16
}

// counted wait: vmcnt(VM6) lgkmcnt(LG) (63/15 = no wait), then sched fence
template<int VM6, int LG>
__device__ __forceinline__ void waitcnt_fence() {
    __builtin_amdgcn_s_waitcnt((VM6 & 15) | ((VM6 >> 4) << 14) | (7 << 4) | (LG << 8));
    __builtin_amdgcn_sched_barrier(0);
}

// Build conv kernel bf16, repacked for contiguous staging:
// Kb2[stage][tap][mo][cs][r][j]: el = ((stage*126+tap)*1024) + mo*256 + cs*128
//   + r*8 + j  (o = mo*16+r, i = stage*16 + cs*8 + j).
// Each (stage,tap) block = 2048 B contiguous; tap 125 zero pad; self-
// interaction folded into center tap 62 (x10, out = 0.1*conv_total).
__global__ __launch_bounds__(256) void build_K(
    const float* __restrict__ w_lin0,
    const float* __restrict__ w_lin1,
    const float* __restrict__ tp_weight,
    unsigned short* __restrict__ Kb2)
{
    const int tid = (int)threadIdx.x;
    const int tap = (int)blockIdx.x;            // 0..125
#define KIDX(o, i) (((((i) >> 4) * 126 + tap) * 1024) + ((o) >> 4) * 256 + \
                    (((i) >> 3) & 1) * 128 + ((o) & 15) * 8 + ((i) & 7))
    if (tap == 125) {
        for (int n = tid; n < 4096; n += 256) {
            int o = n & 63, i = n >> 6;
            Kb2[KIDX(o, i)] = 0;
        }
        return;
    }
    const int i1 = tap / 25, i2 = (tap / 5) % 5, i3 = tap % 5;
    const float X = -1.0f + 0.5f * (float)i1;
    const float Y = -1.0f + 0.5f * (float)i2;
    const float Z = -1.0f + 0.5f * (float)i3;
    const float d = sqrtf(X*X + Y*Y + Z*Z);
    const float dinv = 1.0f / fmaxf(d, 1e-12f);
    const float vx = X * dinv, vy = Y * dinv, vz = Z * dinv;
    const float r2 = vx*vx + vy*vy + vz*vz;

    __shared__ float wsh[1280];
    __shared__ float y1s[3];
    __shared__ float Qs[9];

    if (tid == 0) {
        const float s3 = 1.7320508075688772f;
        const float s15 = 3.872983346207417f;
        y1s[0] = s3 * vy; y1s[1] = s3 * vz; y1s[2] = s3 * vx;
        float y2v0 = s15 * vx * vy;
        float y2v1 = s15 * vy * vz;
        float y2v2 = 1.118033988749895f * (3.0f * vz * vz - r2);
        float y2v3 = s15 * vx * vz;
        float y2v4 = 1.9364916731037085f * (vx * vx - vy * vy);
        const float INV10 = 0.31622776601683794f;
        const float INV30 = 0.18257418583505536f;
        Qs[0] = -y2v2 * INV30 - y2v4 * INV10;
        Qs[4] =  2.0f * y2v2 * INV30;
        Qs[8] = -y2v2 * INV30 + y2v4 * INV10;
        Qs[1] = Qs[3] = y2v1 * INV10;
        Qs[2] = Qs[6] = y2v0 * INV10;
        Qs[5] = Qs[7] = y2v3 * INV10;
    }

    float emb[5];
    #pragma unroll
    for (int e = 0; e < 5; ++e) {
        float t = (d - 0.25f * (float)e) * 4.0f;
        emb[e] = expf(-t * t) * (1.0f / 1.12f);
    }
    const float scale = cosf(3.14159265358979323846f * d) / 11.180339887498949f;

    for (int j = tid; j < 1280; j += 256) {
        float s = 0.0f;
        #pragma unroll
        for (int e = 0; e < 5; ++e) s += emb[e] * tp_weight[e * 1280 + j];
        wsh[j] = scale * s;
    }
    __syncthreads();

    const float F0   = 0.17677669529663687f;
    const float F1   = 0.25f;
    const float F0S3 = 0.10206207261596574f;
    const float F1S3 = 0.14433756729740646f;

    #pragma unroll 1
    for (int n = 0; n < 16; ++n) {
        int e = n * 256 + tid;
        int o = e & 63, i = e >> 6;
        float Kv;
        if (o < 16) {
            if (i < 16) {
                Kv = F0 * wsh[0 * 256 + i * 16 + o];
            } else {
                int u = (i - 16) / 3, a = (i - 16) % 3;
                Kv = F0S3 * y1s[a] * wsh[3 * 256 + u * 16 + o];
            }
        } else {
            int wcol = (o - 16) / 3, c = (o - 16) % 3;
            if (i < 16) {
                Kv = F1S3 * y1s[c] * wsh[1 * 256 + i * 16 + wcol];
            } else {
                int u = (i - 16) / 3, a = (i - 16) % 3;
                Kv = F1 * Qs[a * 3 + c] * wsh[4 * 256 + u * 16 + wcol];
                if (a == c) Kv += F1S3 * wsh[2 * 256 + u * 16 + wcol];
            }
        }
        if (tap == 62) {
            if (o < 16) {
                if (i < 16) Kv += 2.5f * w_lin0[i * 16 + o];
            } else if (i >= 16) {
                int v = (o - 16) / 3, m = (o - 16) % 3;
                int u = (i - 16) / 3, a = (i - 16) % 3;
                if (a == m) Kv += 2.5f * w_lin1[u * 16 + v];
            }
        }
        Kb2[KIDX(o, i)] = (unsigned short)f2bf(Kv);
    }
#undef KIDX
}

// Pre-pass: x fp32 [b][c][32^3] -> xbz bf16 channel-last [b][pos][64ch],
// preceded by a 128B zero page (for OOB halo lanes).
__global__ __launch_bounds__(256) void to_blc(
    const float* __restrict__ x,
    unsigned short* __restrict__ xbz)
{
    const int tid = (int)threadIdx.x, blk = (int)blockIdx.x;
    if (blk == 0 && tid < 64) xbz[tid] = 0;          // zero page
    const int p = blk * 256 + tid;                   // 0..131071
    const int b = p >> 15, pos = p & 32767;
    const float* xp = x + ((size_t)b << 21) + pos;
    unsigned short* op = xbz + 64 + (size_t)p * 64;
    #pragma unroll
    for (int cg = 0; cg < 8; ++cg) {
        u32x4 dv;
        #pragma unroll
        for (int jj = 0; jj < 4; ++jj) {
            float f0 = xp[((size_t)(cg * 8 + 2 * jj)) << 15];
            float f1 = xp[((size_t)(cg * 8 + 2 * jj + 1)) << 15];
            dv[jj] = f2bf(f0) | (f2bf(f1) << 16);
        }
        *(u32x4*)(op + cg * 8) = dv;
    }
}

// One K-step (tap pair P): issue pair-(P+3) Kb DMA into LDS ring slot,
// counted vmcnt + barrier (pair P+1 visible), ds_read A/B(P+1) into reg
// rings, lgkmcnt(8), 16 MFMAs on pair P.
template<int P>
__device__ __forceinline__ void kstep(
    char* lds, const char* kb2s, int tid4, int kbWv,
    const int (&nbase)[4], const int (&sax)[5], bool thv, int abase,
    bf16x8 (&Ar)[2][4], bf16x8 (&Br)[2][4], f32x4 (&acc)[4][4])
{
    if constexpr (P + 3 < 63) {
        const char* src = kb2s + (P + 3) * 4096 + tid4;
        char* dst = lds + KB_LDS + ((P + 3) & 3) * 4096 + kbWv;
        __builtin_amdgcn_global_load_lds(
            (const __attribute__((address_space(1))) unsigned int*)src,
            (__attribute__((address_space(3))) unsigned int*)dst, 4, 0, 0);
        __builtin_amdgcn_global_load_lds(
            (const __attribute__((address_space(1))) unsigned int*)(src + 2048),
            (__attribute__((address_space(3))) unsigned int*)(dst + 2048), 4, 0, 0);
    }
    if constexpr (P < 62) {
        constexpr int VM = (P <= 59) ? 4 : (P == 60) ? 2 : 0;
        waitcnt_fence<VM, 15>();
        __builtin_amdgcn_s_barrier();
        __builtin_amdgcn_sched_barrier(0);
        constexpr int t0 = 2 * (P + 1);
        constexpr int t1 = (t0 + 1 == 125) ? 124 : t0 + 1;
        int pd = thv ? ((t1 / 25) * 4608 + ((t1 / 5) % 5) * 384 + sax[t1 % 5])
                     : ((t0 / 25) * 4608 + ((t0 / 5) % 5) * 384 + sax[t0 % 5]);
        #pragma unroll
        for (int mo = 0; mo < 4; ++mo) {
            int a = KB_LDS + ((P + 1) & 3) * 4096 + abase + mo * 512;
            asm volatile("ds_read_b128 %0, %1" : "=v"(Ar[(P + 1) & 1][mo]) : "v"(a));
        }
        #pragma unroll
        for (int np = 0; np < 4; ++np) {
            int a = nbase[np] + pd;
            asm volatile("ds_read_b128 %0, %1" : "=v"(Br[(P + 1) & 1][np]) : "v"(a));
        }
    }
    waitcnt_fence<63, (P < 62) ? 8 : 0>();
    #pragma unroll
    for (int mo = 0; mo < 4; ++mo)
        #pragma unroll
        for (int np = 0; np < 4; ++np)
            acc[mo][np] = __builtin_amdgcn_mfma_f32_16x16x32_bf16(
                Ar[P & 1][mo], Br[P & 1][np], acc[mo][np], 0, 0, 0);
    if constexpr (P + 1 < 63)
        kstep<P + 1>(lds, kb2s, tid4, kbWv, nbase, sax, thv, abase, Ar, Br, acc);
}

// Implicit-GEMM conv, MFMA 16x16x32 bf16, LDS-staged A (T3/T4 structure).
// grid 256, block 512 thr = 8 waves; tile 8z x 8y x 8x = 512 pos, 64 o.
// Wave = one z-plane: 4 mo x 4 np, acc 64 VGPR. LDS: x halo [12][12][12]x32B
// (XOR-16 swizzle) 54KB + Kb 4-slot pair ring 16KB = 70KB, 1 block/CU.
__global__ __launch_bounds__(512, 2) void conv_mfma(
    const unsigned short* __restrict__ xbz,
    const unsigned short* __restrict__ Kb2,
    float* __restrict__ out)
{
    __shared__ __align__(16) char lds[KB_LDS + 16384];

    const int tid = (int)threadIdx.x;
    const int blk = (int)blockIdx.x;
    const int xt = blk & 3, yt = (blk >> 2) & 3, zt = (blk >> 4) & 3, b = blk >> 6;
    const int lane = tid & 63, wv = tid >> 6;
    const int r = lane & 15, g = lane >> 4;
    const int thalf = g >> 1, chslot = g & 1;
    const bool thv = (thalf != 0);

    // ---- x staging source offsets (1728 pos x 2 slots = 3456 chunks) ----
    unsigned srcOff[7];
    {
        const int gz0 = zt * 8 - 2, gy0 = yt * 8 - 2, gx0 = xt * 8 - 2;
        #pragma unroll
        for (int i = 0; i < 7; ++i) {
            int c = tid + i * 512;
            int pos = c >> 1, slot = c & 1;
            int hz = pos / 144; int rem = pos - hz * 144;
            int hy = rem / 12;  int hx = rem - hy * 12;
            int gz = gz0 + hz, gy = gy0 + hy, gx = gx0 + hx;
            bool ok = ((unsigned)gz < 32u) && ((unsigned)gy < 32u) && ((unsigned)gx < 32u);
            int pg = (gz << 10) + (gy << 5) + gx;
            unsigned chs = (unsigned)(slot ^ ((hx >> 2) & 1));  // swizzle-inverse
            srcOff[i] = ok ? (unsigned)(128 + (((b << 15) + pg) << 7) + chs * 16)
                           : (unsigned)(slot * 16);             // zero page
        }
    }

    // ---- per-lane swizzled x/ch part for dx=0..4 ----
    int sax[5];
    #pragma unroll
    for (int dx = 0; dx < 5; ++dx) {
        int xx = (r & 7) + dx;
        sax[dx] = (xx * 32 + chslot * 16) ^ ((xx & 4) << 2);
    }
    // per-np base (wave z-plane + y part)
    int nbase[4];
    #pragma unroll
    for (int n = 0; n < 4; ++n)
        nbase[n] = wv * 4608 + (2 * n + (r >> 3)) * 384;

    const int abase = thalf * 2048 + chslot * 256 + r * 16;  // A-frag lane base
    const int tid4 = tid * 4;
    const int kbWv = wv * 256;

    f32x4 acc[4][4];
    #pragma unroll
    for (int i = 0; i < 4; ++i)
        #pragma unroll
        for (int j = 0; j < 4; ++j) acc[i][j] = (f32x4)0.0f;

    #pragma unroll 1
    for (int s = 0; s < 4; ++s) {
        const char* kb2s = (const char*)Kb2 + s * 258048;
        __builtin_amdgcn_s_barrier();          // prev stage fully consumed
        __builtin_amdgcn_sched_barrier(0);
        // x staging (current stage slice)
        #pragma unroll
        for (int i = 0; i < 7; ++i) {
            if (i < 6 || tid < 384) {          // wave-uniform guard
                const char* src = (const char*)xbz + srcOff[i] + s * 32;
                __builtin_amdgcn_global_load_lds(
                    (const __attribute__((address_space(1))) unsigned int*)src,
                    (__attribute__((address_space(3))) unsigned int*)
                        (lds + i * 8192 + wv * 1024),
                    16, 0, 0);
            }
        }
        // Kb pairs 0..2 into ring slots 0..2
        #pragma unroll
        for (int p = 0; p < 3; ++p) {
            const char* src = kb2s + p * 4096 + tid4;
            char* dst = lds + KB_LDS + p * 4096 + kbWv;
            __builtin_amdgcn_global_load_lds(
                (const __attribute__((address_space(1))) unsigned int*)src,
                (__attribute__((address_space(3))) unsigned int*)dst, 4, 0, 0);
            __builtin_amdgcn_global_load_lds(
                (const __attribute__((address_space(1))) unsigned int*)(src + 2048),
                (__attribute__((address_space(3))) unsigned int*)(dst + 2048), 4, 0, 0);
        }
        waitcnt_fence<4, 15>();                // x + pair0 done; pairs1,2 pending
        __builtin_amdgcn_s_barrier();
        __builtin_amdgcn_sched_barrier(0);

        // initial reads: pair 0 into ring slot 0
        bf16x8 Ar[2][4], Br[2][4];
        #pragma unroll
        for (int mo = 0; mo < 4; ++mo) {
            int a = KB_LDS + abase + mo * 512;
            asm volatile("ds_read_b128 %0, %1" : "=v"(Ar[0][mo]) : "v"(a));
        }
        {
            int pd0 = thv ? sax[1] : sax[0];
            #pragma unroll
            for (int np = 0; np < 4; ++np) {
                int a = nbase[np] + pd0;
                asm volatile("ds_read_b128 %0, %1" : "=v"(Br[0][np]) : "v"(a));
            }
        }
        kstep<0>(lds, kb2s, tid4, kbWv, nbase, sax, thv, abase, Ar, Br, acc);
    }

    // epilogue: D row = o-in-tile = g*4+reg, col = pos = r (ly = 2np+(r>>3))
    const int gz = zt * 8 + wv;
    #pragma unroll
    for (int mo = 0; mo < 4; ++mo) {
        #pragma unroll
        for (int reg = 0; reg < 4; ++reg) {
            int o = mo * 16 + g * 4 + reg;
            float* op = out + (((size_t)(b * 64 + o)) << 15) + (gz << 10);
            #pragma unroll
            for (int np = 0; np < 4; ++np) {
                int ly = 2 * np + (r >> 3), lx = r & 7;
                op[((yt * 8 + ly) << 5) + (xt * 8 + lx)] = 0.1f * acc[mo][np][reg];
            }
        }
    }
}

extern "C" void kernel_launch(void* const* d_in, const int* in_sizes, int n_in,
                              void* d_out, int out_size, void* d_ws, size_t ws_size,
                              hipStream_t stream) {
    const float* x       = (const float*)d_in[0];
    const float* w_lin0  = (const float*)d_in[1];
    const float* w_lin1  = (const float*)d_in[2];
    const float* tp      = (const float*)d_in[3];
    unsigned short* Kb2 = (unsigned short*)d_ws;                        // ~1.01 MB
    unsigned short* xbz = (unsigned short*)((char*)d_ws + (2u << 20));  // 128B zeros + 16.8MB bf16 x
    float* out = (float*)d_out;

    build_K<<<126, 256, 0, stream>>>(w_lin0, w_lin1, tp, Kb2);
    to_blc<<<512, 256, 0, stream>>>(x, xbz);
    conv_mfma<<<256, 512, 0, stream>>>(xbz, Kb2, out);
}

// Round 11
// 293.574 us; speedup vs baseline: 2.3221x; 1.0875x over previous
//
#include <hip/hip_runtime.h>
#include <math.h>

typedef __attribute__((ext_vector_type(8))) short bf16x8;
typedef __attribute__((ext_vector_type(4))) float f32x4;
typedef __attribute__((ext_vector_type(4))) unsigned int u32x4;

__device__ __forceinline__ unsigned f2bf(float f) {
    union { float f; unsigned u; } v; v.f = f;
    return (v.u + 0x7FFFu + ((v.u >> 16) & 1u)) >> 16;   // RTNE bf16
}

// counted wait: vmcnt(VM6) lgkmcnt(LG) (63/15 = no wait), then sched fence
template<int VM6, int LG>
__device__ __forceinline__ void waitcnt_fence() {
    __builtin_amdgcn_s_waitcnt((VM6 & 15) | ((VM6 >> 4) << 14) | (7 << 4) | (LG << 8));
    __builtin_amdgcn_sched_barrier(0);
}

// Build conv kernel bf16, repacked so each (stage,tap) block is contiguous:
// Kb2 el = ((stage*126+tap)*1024) + mo*256 + cs*128 + r*8 + j
//   (o = mo*16+r, i = stage*16 + cs*8 + j); per tap 2048B, per pair 4096B.
// tap 125 zero pad; self-interaction folded into center tap 62 (x10).
__global__ __launch_bounds__(256) void build_K(
    const float* __restrict__ w_lin0,
    const float* __restrict__ w_lin1,
    const float* __restrict__ tp_weight,
    unsigned short* __restrict__ Kb2)
{
    const int tid = (int)threadIdx.x;
    const int tap = (int)blockIdx.x;            // 0..125
#define KIDX(o, i) (((((i) >> 4) * 126 + tap) * 1024) + ((o) >> 4) * 256 + \
                    (((i) >> 3) & 1) * 128 + ((o) & 15) * 8 + ((i) & 7))
    if (tap == 125) {
        for (int n = tid; n < 4096; n += 256) {
            int o = n & 63, i = n >> 6;
            Kb2[KIDX(o, i)] = 0;
        }
        return;
    }
    const int i1 = tap / 25, i2 = (tap / 5) % 5, i3 = tap % 5;
    const float X = -1.0f + 0.5f * (float)i1;
    const float Y = -1.0f + 0.5f * (float)i2;
    const float Z = -1.0f + 0.5f * (float)i3;
    const float d = sqrtf(X*X + Y*Y + Z*Z);
    const float dinv = 1.0f / fmaxf(d, 1e-12f);
    const float vx = X * dinv, vy = Y * dinv, vz = Z * dinv;
    const float r2 = vx*vx + vy*vy + vz*vz;

    __shared__ float wsh[1280];
    __shared__ float y1s[3];
    __shared__ float Qs[9];

    if (tid == 0) {
        const float s3 = 1.7320508075688772f;
        const float s15 = 3.872983346207417f;
        y1s[0] = s3 * vy; y1s[1] = s3 * vz; y1s[2] = s3 * vx;
        float y2v0 = s15 * vx * vy;
        float y2v1 = s15 * vy * vz;
        float y2v2 = 1.118033988749895f * (3.0f * vz * vz - r2);
        float y2v3 = s15 * vx * vz;
        float y2v4 = 1.9364916731037085f * (vx * vx - vy * vy);
        const float INV10 = 0.31622776601683794f;
        const float INV30 = 0.18257418583505536f;
        Qs[0] = -y2v2 * INV30 - y2v4 * INV10;
        Qs[4] =  2.0f * y2v2 * INV30;
        Qs[8] = -y2v2 * INV30 + y2v4 * INV10;
        Qs[1] = Qs[3] = y2v1 * INV10;
        Qs[2] = Qs[6] = y2v0 * INV10;
        Qs[5] = Qs[7] = y2v3 * INV10;
    }

    float emb[5];
    #pragma unroll
    for (int e = 0; e < 5; ++e) {
        float t = (d - 0.25f * (float)e) * 4.0f;
        emb[e] = expf(-t * t) * (1.0f / 1.12f);
    }
    const float scale = cosf(3.14159265358979323846f * d) / 11.180339887498949f;

    for (int j = tid; j < 1280; j += 256) {
        float s = 0.0f;
        #pragma unroll
        for (int e = 0; e < 5; ++e) s += emb[e] * tp_weight[e * 1280 + j];
        wsh[j] = scale * s;
    }
    __syncthreads();

    const float F0   = 0.17677669529663687f;
    const float F1   = 0.25f;
    const float F0S3 = 0.10206207261596574f;
    const float F1S3 = 0.14433756729740646f;

    #pragma unroll 1
    for (int n = 0; n < 16; ++n) {
        int e = n * 256 + tid;
        int o = e & 63, i = e >> 6;
        float Kv;
        if (o < 16) {
            if (i < 16) {
                Kv = F0 * wsh[0 * 256 + i * 16 + o];
            } else {
                int u = (i - 16) / 3, a = (i - 16) % 3;
                Kv = F0S3 * y1s[a] * wsh[3 * 256 + u * 16 + o];
            }
        } else {
            int wcol = (o - 16) / 3, c = (o - 16) % 3;
            if (i < 16) {
                Kv = F1S3 * y1s[c] * wsh[1 * 256 + i * 16 + wcol];
            } else {
                int u = (i - 16) / 3, a = (i - 16) % 3;
                Kv = F1 * Qs[a * 3 + c] * wsh[4 * 256 + u * 16 + wcol];
                if (a == c) Kv += F1S3 * wsh[2 * 256 + u * 16 + wcol];
            }
        }
        if (tap == 62) {
            if (o < 16) {
                if (i < 16) Kv += 2.5f * w_lin0[i * 16 + o];
            } else if (i >= 16) {
                int v = (o - 16) / 3, m = (o - 16) % 3;
                int u = (i - 16) / 3, a = (i - 16) % 3;
                if (a == m) Kv += 2.5f * w_lin1[u * 16 + v];
            }
        }
        Kb2[KIDX(o, i)] = (unsigned short)f2bf(Kv);
    }
#undef KIDX
}

// Pre-pass: x fp32 [b][c][32^3] -> xbz bf16 channel-last [b][pos][64ch],
// preceded by a 128B zero page (for OOB halo lanes).
__global__ __launch_bounds__(256) void to_blc(
    const float* __restrict__ x,
    unsigned short* __restrict__ xbz)
{
    const int tid = (int)threadIdx.x, blk = (int)blockIdx.x;
    if (blk == 0 && tid < 64) xbz[tid] = 0;          // zero page
    const int p = blk * 256 + tid;                   // 0..131071
    const int b = p >> 15, pos = p & 32767;
    const float* xp = x + ((size_t)b << 21) + pos;
    unsigned short* op = xbz + 64 + (size_t)p * 64;
    #pragma unroll
    for (int cg = 0; cg < 8; ++cg) {
        u32x4 dv;
        #pragma unroll
        for (int jj = 0; jj < 4; ++jj) {
            float f0 = xp[((size_t)(cg * 8 + 2 * jj)) << 15];
            float f1 = xp[((size_t)(cg * 8 + 2 * jj + 1)) << 15];
            dv[jj] = f2bf(f0) | (f2bf(f1) << 16);
        }
        *(u32x4*)(op + cg * 8) = dv;
    }
}

// One K-step (tap pair P): issue A-pair P+3 global->reg (4-slot ring, dist 3,
// fully-coalesced 4KB pair block), ds_read Br pair P+1 (2-slot ring), counted
// vmcnt(12)/lgkmcnt(4), 16 MFMAs on pair P. No barriers.
template<int P>
__device__ __forceinline__ void kstep(
    const char* kb2s, int klaneA,
    const int (&nbase)[4], const int (&sax)[5], bool thv,
    bf16x8 (&Ar)[4][4], bf16x8 (&Br)[2][4], f32x4 (&acc)[4][4])
{
    if constexpr (P + 3 < 63) {
        #pragma unroll
        for (int mo = 0; mo < 4; ++mo) {
            unsigned voff = (unsigned)(klaneA + (P + 3) * 4096 + mo * 512);
            asm volatile("global_load_dwordx4 %0, %1, %2"
                         : "=v"(Ar[(P + 3) & 3][mo]) : "v"(voff), "s"(kb2s));
        }
    }
    if constexpr (P + 1 < 63) {
        constexpr int t0 = 2 * (P + 1);
        constexpr int t1 = (t0 + 1 == 125) ? 124 : t0 + 1;
        int pd = thv ? ((t1 / 25) * 4608 + ((t1 / 5) % 5) * 384 + sax[t1 % 5])
                     : ((t0 / 25) * 4608 + ((t0 / 5) % 5) * 384 + sax[t0 % 5]);
        #pragma unroll
        for (int np = 0; np < 4; ++np) {
            int a = nbase[np] + pd;
            asm volatile("ds_read_b128 %0, %1" : "=v"(Br[(P + 1) & 1][np]) : "v"(a));
        }
    }
    constexpr int VM = (P + 3 < 63) ? 12 : (62 - P) * 4;
    constexpr int LG = (P < 62) ? 4 : 0;
    waitcnt_fence<VM, LG>();
    #pragma unroll
    for (int mo = 0; mo < 4; ++mo)
        #pragma unroll
        for (int np = 0; np < 4; ++np)
            acc[mo][np] = __builtin_amdgcn_mfma_f32_16x16x32_bf16(
                Ar[P & 3][mo], Br[P & 1][np], acc[mo][np], 0, 0, 0);
    if constexpr (P + 1 < 63)
        kstep<P + 1>(kb2s, klaneA, nbase, sax, thv, Ar, Br, acc);
}

// Implicit-GEMM conv, MFMA 16x16x32 bf16. A: global->reg asm ring (Kb2
// coalesced pair blocks, L2-served). B: x halo in LDS (XOR-16 swizzle),
// staged once per stage via global_load_lds. 2 barriers/stage only.
// grid 512 (4xt * 4yt * 8zt * 4b), block 256 thr = 4 waves; tile 4z x 8y x
// 8x; wave = z-plane, M=64 o x N=64 pos, acc[4][4]. ~190 VGPR, 2 blocks/CU.
__global__ __launch_bounds__(256, 2) void conv_mfma(
    const unsigned short* __restrict__ xbz,
    const unsigned short* __restrict__ Kb2,
    float* __restrict__ out)
{
    __shared__ __align__(16) char xs[36864];   // [8z][12y][12x] * 32B

    const int tid = (int)threadIdx.x;
    const int blk = (int)blockIdx.x;
    const int xt = blk & 3, yt = (blk >> 2) & 3, zt = (blk >> 4) & 7, b = blk >> 7;
    const int lane = tid & 63, wv = tid >> 6;
    const int r = lane & 15, g = lane >> 4;
    const int thalf = g >> 1, chslot = g & 1;
    const bool thv = (thalf != 0);

    // ---- x staging source offsets (9 chunks/thread), round-3 pattern ----
    unsigned srcOff[9];
    {
        const int gz0 = zt * 4 - 2, gy0 = yt * 8 - 2, gx0 = xt * 8 - 2;
        #pragma unroll
        for (int i = 0; i < 9; ++i) {
            int pos = wv * 288 + i * 32 + (lane >> 1);     // 0..1151
            int hz = pos / 144; int rem = pos - hz * 144;
            int hy = rem / 12;  int hx = rem - hy * 12;
            int gz = gz0 + hz, gy = gy0 + hy, gx = gx0 + hx;
            bool ok = ((unsigned)gz < 32u) && ((unsigned)gy < 32u) && ((unsigned)gx < 32u);
            int pg = (gz << 10) + (gy << 5) + gx;
            unsigned chs = (unsigned)((lane & 1) ^ ((hx >> 2) & 1));  // swizzle-inverse
            srcOff[i] = ok ? (unsigned)(128 + (((b << 15) + pg) << 7) + chs * 16)
                           : (unsigned)((lane & 1) * 16);             // zero page
        }
    }

    // ---- per-lane swizzled x/ch part for dx=0..4 ----
    int sax[5];
    #pragma unroll
    for (int dx = 0; dx < 5; ++dx) {
        int xx = (r & 7) + dx;
        sax[dx] = (xx * 32 + chslot * 16) ^ ((xx & 4) << 2);
    }
    // per-np base (wave z-plane + y part)
    int nbase[4];
    #pragma unroll
    for (int n = 0; n < 4; ++n)
        nbase[n] = wv * 4608 + (2 * n + (r >> 3)) * 384;

    // A lane base within a 4KB pair block (thalf picks tap-in-pair)
    const int klaneA = thalf * 2048 + chslot * 256 + r * 16;

    f32x4 acc[4][4];
    #pragma unroll
    for (int i = 0; i < 4; ++i)
        #pragma unroll
        for (int j = 0; j < 4; ++j) acc[i][j] = (f32x4)0.0f;

    #pragma unroll 1
    for (int s = 0; s < 4; ++s) {
        const char* kb2s = (const char*)Kb2 + s * 258048;   // 126*2048

        __builtin_amdgcn_s_barrier();          // prev stage LDS reads done
        __builtin_amdgcn_sched_barrier(0);
        // x staging (this stage's 16-ch slice), 9 DMAs -> vmcnt +9
        #pragma unroll
        for (int i = 0; i < 9; ++i) {
            const char* src = (const char*)xbz + srcOff[i] + s * 32;
            __builtin_amdgcn_global_load_lds(
                (const __attribute__((address_space(1))) unsigned int*)src,
                (__attribute__((address_space(3))) unsigned int*)
                    (xs + wv * 9216 + i * 1024),
                16, 0, 0);
        }
        __builtin_amdgcn_sched_barrier(0);

        // A ring prologue: pairs 0..2 (12 loads) AFTER x in the vm queue
        bf16x8 Ar[4][4];
        bf16x8 Br[2][4];
        #pragma unroll
        for (int pf = 0; pf < 3; ++pf)
            #pragma unroll
            for (int mo = 0; mo < 4; ++mo) {
                unsigned voff = (unsigned)(klaneA + pf * 4096 + mo * 512);
                asm volatile("global_load_dwordx4 %0, %1, %2"
                             : "=v"(Ar[pf][mo]) : "v"(voff), "s"(kb2s));
            }
        __builtin_amdgcn_sched_barrier(0);

        waitcnt_fence<12, 15>();               // x landed; 12 A-loads in flight
        __builtin_amdgcn_s_barrier();          // all waves' x landed
        __builtin_amdgcn_sched_barrier(0);

        // Br pair 0 (taps 0: dx=0 / 1: dx=1)
        {
            int pd0 = thv ? sax[1] : sax[0];
            #pragma unroll
            for (int np = 0; np < 4; ++np) {
                int a = nbase[np] + pd0;
                asm volatile("ds_read_b128 %0, %1" : "=v"(Br[0][np]) : "v"(a));
            }
        }
        kstep<0>(kb2s, klaneA, nbase, sax, thv, Ar, Br, acc);
    }

    // epilogue: D row = o-in-tile = g*4+reg, col = pos-in-plane = r
    const int gz = zt * 4 + wv;
    #pragma unroll
    for (int mo = 0; mo < 4; ++mo) {
        #pragma unroll
        for (int reg = 0; reg < 4; ++reg) {
            int o = mo * 16 + g * 4 + reg;
            float* op = out + (((size_t)(b * 64 + o)) << 15) + (gz << 10);
            #pragma unroll
            for (int np = 0; np < 4; ++np) {
                int ly = 2 * np + (r >> 3), lx = r & 7;
                op[((yt * 8 + ly) << 5) + (xt * 8 + lx)] = 0.1f * acc[mo][np][reg];
            }
        }
    }
}

extern "C" void kernel_launch(void* const* d_in, const int* in_sizes, int n_in,
                              void* d_out, int out_size, void* d_ws, size_t ws_size,
                              hipStream_t stream) {
    const float* x       = (const float*)d_in[0];
    const float* w_lin0  = (const float*)d_in[1];
    const float* w_lin1  = (const float*)d_in[2];
    const float* tp      = (const float*)d_in[3];
    unsigned short* Kb2 = (unsigned short*)d_ws;                        // ~1.01 MB
    unsigned short* xbz = (unsigned short*)((char*)d_ws + (2u << 20));  // 128B zeros + 16.8MB bf16 x
    float* out = (float*)d_out;

    build_K<<<126, 256, 0, stream>>>(w_lin0, w_lin1, tp, Kb2);
    to_blc<<<512, 256, 0, stream>>>(x, xbz);
    conv_mfma<<<512, 256, 0, stream>>>(xbz, Kb2, out);
}